// Round 2
// baseline (311.962 us; speedup 1.0000x reference)
//
#include <hip/hip_runtime.h>
#include <stdint.h>

// Problem constants (B=4, S=4096, D_IN=2048, D_OUT=2048, DELTA_A=0, DELTA_W=0.05)
#define K_DIM   2048
#define N_DIM   2048
#define M_DIM   16384   // B*S
#define DELTA_W 0.05f

// R4: 256x256 tile, BK=128 i8, provable 2-phase double-buffer.
// (R3's 4-phase counted-vmcnt raced: phase 1 reads span ALL half-tiles
// because waves are spread over both M-halves and all N-quarters, so the
// whole next tile must be resident at each group boundary.)
#define BM 256
#define BN 256
#define BK 128
#define NT (K_DIM / BK)   // 16 K-tiles

typedef __attribute__((ext_vector_type(4))) int i32x4;

// ---------------------------------------------------------------------------
// async global->LDS, 16B per lane. LDS dest must be wave-uniform base + lane*16.
__device__ __forceinline__ void async_copy16(const void* g, void* l) {
    __builtin_amdgcn_global_load_lds(
        (__attribute__((address_space(1))) void*)g,
        (__attribute__((address_space(3))) void*)l,
        16, 0, 0);
}

// 256-thread block sum (4 waves of 64)
__device__ __forceinline__ float block_sum_256(float v, float* sm) {
#pragma unroll
    for (int o = 32; o > 0; o >>= 1) v += __shfl_down(v, o, 64);
    const int lane = threadIdx.x & 63;
    const int w    = threadIdx.x >> 6;
    __syncthreads();              // protect sm reuse across calls
    if (lane == 0) sm[w] = v;
    __syncthreads();
    return sm[0] + sm[1] + sm[2] + sm[3];
}

// ---------------------------------------------------------------------------
// Fused quantization kernel (unchanged — passed R0/R2).
__global__ __launch_bounds__(256) void quant_kernel(
    const float* __restrict__ W, const float* __restrict__ x,
    int8_t* __restrict__ code, float* __restrict__ alpha,
    int8_t* __restrict__ xq)
{
    __shared__ float sm[4];
    const int t = threadIdx.x;

    if (blockIdx.x < N_DIM) {
        // ---- weight ternarization ----
        const int row = blockIdx.x;
        const float* Wr = W + (size_t)row * K_DIM;

        float v[8];
        float s = 0.f;
#pragma unroll
        for (int i = 0; i < 8; ++i) { v[i] = Wr[t + i * 256]; s += v[i]; }
        const float mean = block_sum_256(s, sm) * (1.0f / K_DIM);

        float sa = 0.f;
#pragma unroll
        for (int i = 0; i < 8; ++i) sa += fabsf(v[i] - mean);
        const float thr = DELTA_W * (block_sum_256(sa, sm) * (1.0f / K_DIM));

        float ssum = 0.f, scnt = 0.f;
        int8_t q[8];
#pragma unroll
        for (int i = 0; i < 8; ++i) {
            const float c = v[i] - mean;
            const float a = fabsf(c);
            int8_t qv = 0;
            if (a >= thr) qv = (int8_t)((c > 0.f) - (c < 0.f));
            q[i] = qv;
            if (qv != 0) { ssum += a; scnt += 1.0f; }
        }
        const float num = block_sum_256(ssum, sm);
        const float den = block_sum_256(scnt, sm);
        if (t == 0) alpha[row] = num / fmaxf(den, 1.0f);

#pragma unroll
        for (int i = 0; i < 8; ++i)
            code[(size_t)row * K_DIM + t + i * 256] = q[i];
    } else {
        // ---- activation sign pass: 4 float4 per thread, coalesced ----
        const int blk = blockIdx.x - N_DIM;       // 0..8191
        const int base = blk * 1024 + t;          // float4-group index
        const float4* xin = (const float4*)x;
        char4* xo = (char4*)xq;
#pragma unroll
        for (int i = 0; i < 4; ++i) {
            const float4 f = xin[base + i * 256];
            char4 c;
            c.x = (char)((f.x > 0.f) - (f.x < 0.f));
            c.y = (char)((f.y > 0.f) - (f.y < 0.f));
            c.z = (char)((f.z > 0.f) - (f.z < 0.f));
            c.w = (char)((f.w > 0.f) - (f.w < 0.f));
            xo[base + i * 256] = c;
        }
    }
}

// ---------------------------------------------------------------------------
// Ternary GEMM, 256^2 tile, BK=128, 2-phase double-buffered pipeline.
//
// Geometry: 512 threads = 8 waves (2M x 4N), per-wave output 128x64 =
// 8x4 grid of 16x16x64 i8 MFMAs (64 MFMA per wave per K-tile). LDS: A,B
// tiles 256x128B double-buffered = 128 KiB (1 block/CU, 8 waves).
//
// LDS swizzle (verified 0 bank conflicts in R2): row stride 128B = 8 chunks
// of 16B; chunk cg of row r lives at slot cg^(r&7). Applied on the GLOBAL
// source address so the LDS dest stays lane-linear (global_load_lds
// requirement); fragment reads XOR the same pattern back.
//
// Pipeline (per K-tile group t, buffers bp=t&1, nb=bp^1):
//   STAGE tile t+1 -> nb            (8 global_load_lds issues per wave)
//   s_waitcnt vmcnt(8); s_barrier   <- drains exactly tile t's 8 loads,
//                                      which were issued one FULL group
//                                      (64 MFMAs ~ 500cy) earlier; the 8
//                                      just-issued loads stay in flight
//   ds_read frags + 64 MFMA from bp (compiler schedules freely, lgkm
//                                      waits auto-inserted by data deps)
//   s_barrier                        <- all waves done READING bp before
//                                      anyone stages into bp next group
// RAW: every group's vmcnt(8) has <=16 outstanding -> waits current tile.
// WAR: stages into a buffer are only issued after the end-barrier of the
// group that last read it. Last group stages nothing -> vmcnt(0).
__global__ __launch_bounds__(512) void gemm_kernel(
    const int8_t* __restrict__ A, const int8_t* __restrict__ Bt,
    const float* __restrict__ alpha, const float* __restrict__ bias,
    float* __restrict__ out)
{
    __shared__ __align__(16) int8_t As[2][BM * BK];   // 2 x 32 KiB
    __shared__ __align__(16) int8_t Bs[2][BN * BK];   // 2 x 32 KiB

    const int tid  = threadIdx.x;          // 0..511
    const int lane = tid & 63;
    const int wv   = tid >> 6;             // wave 0..7
    const int wm   = (wv >> 2) * 128;      // wave m-offset: 0 / 128
    const int wn   = (wv & 3) * 64;        // wave n-offset: 0,64,128,192
    const int fr   = lane & 15;            // fragment row within 16
    const int q    = lane >> 4;            // k-quad 0..3 (16B each)
    const int c0   = q ^ (fr & 7);         // swizzled chunk slot, kk=0

    const int tileM = blockIdx.y * BM;
    const int tileN = blockIdx.x * BN;

    // staging source byte offsets [half][issue]: slot s = e*512+tid,
    // row r = s>>3, global chunk cg = (s&7) ^ (r&7) (inverse swizzle).
    size_t a_src[2][2], b_src[2][2];
#pragma unroll
    for (int e = 0; e < 2; ++e) {
        const int s  = e * 512 + tid;
        const int r  = s >> 3;
        const int cg = (s & 7) ^ (r & 7);
#pragma unroll
        for (int h = 0; h < 2; ++h) {
            a_src[h][e] = (size_t)(tileM + h * 128 + r) * K_DIM + cg * 16;
            b_src[h][e] = (size_t)(tileN + h * 128 + r) * K_DIM + cg * 16;
        }
    }

    i32x4 acc[8][4] = {};
    i32x4 af[2][4], bf0[2][2], bf1[2][2];  // [kk][frag]

#define STAGE_A(nbp, h, kk0) do {                                              \
    async_copy16(A  + a_src[h][0] + (kk0), &As[nbp][(h) * 16384 + tid * 16]);  \
    async_copy16(A  + a_src[h][1] + (kk0),                                     \
                 &As[nbp][(h) * 16384 + 8192 + tid * 16]);                     \
} while (0)
#define STAGE_B(nbp, h, kk0) do {                                              \
    async_copy16(Bt + b_src[h][0] + (kk0), &Bs[nbp][(h) * 16384 + tid * 16]);  \
    async_copy16(Bt + b_src[h][1] + (kk0),                                     \
                 &Bs[nbp][(h) * 16384 + 8192 + tid * 16]);                     \
} while (0)

    // ---- prologue: stage tile 0 into buf0 (8 loads in flight) ----
    STAGE_A(0, 0, 0); STAGE_B(0, 0, 0);
    STAGE_B(0, 1, 0); STAGE_A(0, 1, 0);

    int k1 = 0;

#define GROUP(bp, DS, WV) {                                                    \
    const int8_t* Ac = As[(bp)];                                               \
    const int8_t* Bc = Bs[(bp)];                                               \
    const int nb = (bp) ^ 1;                                                   \
    if (DS) { STAGE_A(nb, 0, k1); STAGE_B(nb, 0, k1);                          \
              STAGE_B(nb, 1, k1); STAGE_A(nb, 1, k1); }                        \
    asm volatile("s_waitcnt vmcnt(" WV ")\n\ts_barrier" ::: "memory");         \
    /* ---- fragment reads: A m-half0, all B ---- */                           \
    _Pragma("unroll")                                                          \
    for (int i = 0; i < 4; ++i) {                                              \
        const int r8 = (wm + i * 16 + fr) * 128;                               \
        af[0][i] = *(const i32x4*)(Ac + r8 + c0 * 16);                         \
        af[1][i] = *(const i32x4*)(Ac + r8 + (c0 ^ 4) * 16);                   \
    }                                                                          \
    _Pragma("unroll")                                                          \
    for (int j = 0; j < 2; ++j) {                                              \
        const int r8a = (wn + j * 16 + fr) * 128;                              \
        bf0[0][j] = *(const i32x4*)(Bc + r8a + c0 * 16);                       \
        bf0[1][j] = *(const i32x4*)(Bc + r8a + (c0 ^ 4) * 16);                 \
        const int r8b = (wn + 32 + j * 16 + fr) * 128;                         \
        bf1[0][j] = *(const i32x4*)(Bc + r8b + c0 * 16);                       \
        bf1[1][j] = *(const i32x4*)(Bc + r8b + (c0 ^ 4) * 16);                 \
    }                                                                          \
    /* ---- 32 MFMAs: m-half0 x {n0,n1} ---- */                                \
    _Pragma("unroll")                                                          \
    for (int i = 0; i < 4; ++i) {                                              \
        _Pragma("unroll")                                                      \
        for (int j = 0; j < 2; ++j) {                                          \
            acc[i][j] = __builtin_amdgcn_mfma_i32_16x16x64_i8(                 \
                af[0][i], bf0[0][j], acc[i][j], 0, 0, 0);                      \
            acc[i][j] = __builtin_amdgcn_mfma_i32_16x16x64_i8(                 \
                af[1][i], bf0[1][j], acc[i][j], 0, 0, 0);                      \
            acc[i][j + 2] = __builtin_amdgcn_mfma_i32_16x16x64_i8(             \
                af[0][i], bf1[0][j], acc[i][j + 2], 0, 0, 0);                  \
            acc[i][j + 2] = __builtin_amdgcn_mfma_i32_16x16x64_i8(             \
                af[1][i], bf1[1][j], acc[i][j + 2], 0, 0, 0);                  \
        }                                                                      \
    }                                                                          \
    /* ---- fragment reads: A m-half1 (reuse af regs) ---- */                  \
    _Pragma("unroll")                                                          \
    for (int i = 0; i < 4; ++i) {                                              \
        const int r8 = (wm + 64 + i * 16 + fr) * 128;                          \
        af[0][i] = *(const i32x4*)(Ac + r8 + c0 * 16);                         \
        af[1][i] = *(const i32x4*)(Ac + r8 + (c0 ^ 4) * 16);                   \
    }                                                                          \
    /* ---- 32 MFMAs: m-half1 x {n0,n1} ---- */                                \
    _Pragma("unroll")                                                          \
    for (int i = 0; i < 4; ++i) {                                              \
        _Pragma("unroll")                                                      \
        for (int j = 0; j < 2; ++j) {                                          \
            acc[i + 4][j] = __builtin_amdgcn_mfma_i32_16x16x64_i8(             \
                af[0][i], bf0[0][j], acc[i + 4][j], 0, 0, 0);                  \
            acc[i + 4][j] = __builtin_amdgcn_mfma_i32_16x16x64_i8(             \
                af[1][i], bf0[1][j], acc[i + 4][j], 0, 0, 0);                  \
            acc[i + 4][j + 2] = __builtin_amdgcn_mfma_i32_16x16x64_i8(         \
                af[0][i], bf1[0][j], acc[i + 4][j + 2], 0, 0, 0);              \
            acc[i + 4][j + 2] = __builtin_amdgcn_mfma_i32_16x16x64_i8(         \
                af[1][i], bf1[1][j], acc[i + 4][j + 2], 0, 0, 0);              \
        }                                                                      \
    }                                                                          \
    /* all reads of bp done (lgkm drained by MFMA data deps) */                \
    asm volatile("s_barrier" ::: "memory");                                    \
}

#pragma unroll 1
    for (int t = 0; t < NT - 1; ++t) {
        k1 = (t + 1) * BK;
        GROUP(t & 1, 1, "8");
    }
    GROUP((NT - 1) & 1, 0, "0");

#undef GROUP
#undef STAGE_A
#undef STAGE_B

    // ---- epilogue: C/D layout col=lane&15, row=(lane>>4)*4+reg ----
    const int cl = lane & 15;
    const int qr = lane >> 4;
#pragma unroll
    for (int j = 0; j < 4; ++j) {
        const int n  = tileN + wn + j * 16 + cl;
        const float al = alpha[n];
        const float bi = bias[n];
#pragma unroll
        for (int i = 0; i < 8; ++i) {
            const int mbase = tileM + wm + i * 16 + qr * 4;
#pragma unroll
            for (int r = 0; r < 4; ++r) {
                out[(size_t)(mbase + r) * N_DIM + n] =
                    al * (float)acc[i][j][r] + bi;
            }
        }
    }
}

// ---------------------------------------------------------------------------
extern "C" void kernel_launch(void* const* d_in, const int* in_sizes, int n_in,
                              void* d_out, int out_size, void* d_ws, size_t ws_size,
                              hipStream_t stream) {
    const float* x = (const float*)d_in[0];   // [4,4096,2048] fp32
    const float* W = (const float*)d_in[1];   // [2048,2048]  fp32
    const float* b = (const float*)d_in[2];   // [2048]       fp32
    float* out = (float*)d_out;               // [4,4096,2048] fp32

    // workspace layout: xq (32 MiB) | wcode (4 MiB) | alpha (8 KiB)
    int8_t* xq    = (int8_t*)d_ws;
    int8_t* wcode = xq + (size_t)M_DIM * K_DIM;
    float*  alpha = (float*)(wcode + (size_t)N_DIM * K_DIM);

    // 2048 wquant blocks + 8192 xquant blocks in one launch
    quant_kernel<<<N_DIM + 8192, 256, 0, stream>>>(W, x, wcode, alpha, xq);

    dim3 grid(N_DIM / BN, M_DIM / BM);   // (8, 64) = 512 blocks
    gemm_kernel<<<grid, dim3(512), 0, stream>>>(xq, wcode, alpha, b, out);
}

// Round 3
// 307.236 us; speedup vs baseline: 1.0154x; 1.0154x over previous
//
#include <hip/hip_runtime.h>
#include <stdint.h>

// Problem constants (B=4, S=4096, D_IN=2048, D_OUT=2048, DELTA_A=0, DELTA_W=0.05)
#define K_DIM   2048
#define N_DIM   2048
#define M_DIM   16384   // B*S
#define DELTA_W 0.05f

// R5: 128x256 tile, BK=64, 2 blocks/CU. R4's verified 2-phase counted-vmcnt
// sync structure, shrunk so two blocks co-reside per CU (48 KiB LDS, <=128
// regs) — R4's counters showed latency/sync-bound lockstep at 1 block/CU
// (MfmaUtil 28%, HBM 36%, VALU 14%, conflicts 0: nothing saturated).
#define BM 128
#define BN 256
#define BK 64
#define NT (K_DIM / BK)   // 32 K-tiles

typedef __attribute__((ext_vector_type(4))) int i32x4;

// ---------------------------------------------------------------------------
// async global->LDS, 16B per lane. LDS dest must be wave-uniform base + lane*16.
__device__ __forceinline__ void async_copy16(const void* g, void* l) {
    __builtin_amdgcn_global_load_lds(
        (__attribute__((address_space(1))) void*)g,
        (__attribute__((address_space(3))) void*)l,
        16, 0, 0);
}

// 256-thread block sum (4 waves of 64)
__device__ __forceinline__ float block_sum_256(float v, float* sm) {
#pragma unroll
    for (int o = 32; o > 0; o >>= 1) v += __shfl_down(v, o, 64);
    const int lane = threadIdx.x & 63;
    const int w    = threadIdx.x >> 6;
    __syncthreads();              // protect sm reuse across calls
    if (lane == 0) sm[w] = v;
    __syncthreads();
    return sm[0] + sm[1] + sm[2] + sm[3];
}

// ---------------------------------------------------------------------------
// Fused quantization kernel (unchanged — verified, not the bottleneck).
__global__ __launch_bounds__(256) void quant_kernel(
    const float* __restrict__ W, const float* __restrict__ x,
    int8_t* __restrict__ code, float* __restrict__ alpha,
    int8_t* __restrict__ xq)
{
    __shared__ float sm[4];
    const int t = threadIdx.x;

    if (blockIdx.x < N_DIM) {
        // ---- weight ternarization ----
        const int row = blockIdx.x;
        const float* Wr = W + (size_t)row * K_DIM;

        float v[8];
        float s = 0.f;
#pragma unroll
        for (int i = 0; i < 8; ++i) { v[i] = Wr[t + i * 256]; s += v[i]; }
        const float mean = block_sum_256(s, sm) * (1.0f / K_DIM);

        float sa = 0.f;
#pragma unroll
        for (int i = 0; i < 8; ++i) sa += fabsf(v[i] - mean);
        const float thr = DELTA_W * (block_sum_256(sa, sm) * (1.0f / K_DIM));

        float ssum = 0.f, scnt = 0.f;
        int8_t q[8];
#pragma unroll
        for (int i = 0; i < 8; ++i) {
            const float c = v[i] - mean;
            const float a = fabsf(c);
            int8_t qv = 0;
            if (a >= thr) qv = (int8_t)((c > 0.f) - (c < 0.f));
            q[i] = qv;
            if (qv != 0) { ssum += a; scnt += 1.0f; }
        }
        const float num = block_sum_256(ssum, sm);
        const float den = block_sum_256(scnt, sm);
        if (t == 0) alpha[row] = num / fmaxf(den, 1.0f);

#pragma unroll
        for (int i = 0; i < 8; ++i)
            code[(size_t)row * K_DIM + t + i * 256] = q[i];
    } else {
        // ---- activation sign pass: 4 float4 per thread, coalesced ----
        const int blk = blockIdx.x - N_DIM;       // 0..8191
        const int base = blk * 1024 + t;          // float4-group index
        const float4* xin = (const float4*)x;
        char4* xo = (char4*)xq;
#pragma unroll
        for (int i = 0; i < 4; ++i) {
            const float4 f = xin[base + i * 256];
            char4 c;
            c.x = (char)((f.x > 0.f) - (f.x < 0.f));
            c.y = (char)((f.y > 0.f) - (f.y < 0.f));
            c.z = (char)((f.z > 0.f) - (f.z < 0.f));
            c.w = (char)((f.w > 0.f) - (f.w < 0.f));
            xo[base + i * 256] = c;
        }
    }
}

// ---------------------------------------------------------------------------
// Ternary GEMM, 128x256 tile, BK=64, 2-phase double-buffered pipeline.
//
// Geometry: 512 threads = 8 waves (2M x 4N), per-wave output 64x64 =
// 4x4 grid of 16x16x64 i8 MFMAs (16 MFMA per wave per K-tile). LDS: A tile
// 128x64B (8 KiB) + B tile 256x64B (16 KiB), double-buffered = 48 KiB.
// __launch_bounds__(512,4) targets <=128 regs -> 2 blocks/CU (16 waves),
// so cross-block TLP hides the barrier/vmcnt windows R4 exposed.
//
// LDS swizzle for 64B rows (4 chunks of 16B): chunk cg of row r lives at
// slot cg ^ ((r>>1)&3). (XOR with (r&3) would leave a 4-way conflict; this
// variant spreads 16 consecutive rows over all 8 chunk-columns -> 2-way =
// free, m136.) Applied on the GLOBAL source address so the LDS dest stays
// lane-linear (global_load_lds requirement); reads XOR the same key, which
// reduces to (fr>>1)&3 — loop-invariant per lane.
//
// Pipeline (per K-tile t, buffers bp=t&1, nb=bp^1) — verified in R4:
//   STAGE tile t+1 -> nb              (3 global_load_lds per thread)
//   s_waitcnt vmcnt(3); s_barrier     <- drains exactly tile t's 3 loads,
//                                        issued one full group earlier; the
//                                        3 just-issued loads stay in flight
//   ds_read frags + 16 MFMA from bp
//   s_barrier                         <- all waves done reading bp before
//                                        anyone stages into bp next group
__global__ __launch_bounds__(512, 4) void gemm_kernel(
    const int8_t* __restrict__ A, const int8_t* __restrict__ Bt,
    const float* __restrict__ alpha, const float* __restrict__ bias,
    float* __restrict__ out)
{
    __shared__ __align__(16) int8_t As[2][BM * BK];   // 2 x 8 KiB
    __shared__ __align__(16) int8_t Bs[2][BN * BK];   // 2 x 16 KiB

    const int tid  = threadIdx.x;          // 0..511
    const int lane = tid & 63;
    const int wv   = tid >> 6;             // wave 0..7
    const int wm   = (wv >> 2) * 64;       // wave m-offset: 0 / 64
    const int wn   = (wv & 3) * 64;        // wave n-offset: 0,64,128,192
    const int fr   = lane & 15;            // fragment row within 16
    const int q    = lane >> 4;            // k-quad 0..3 (16B each)
    const int cs16 = (q ^ ((fr >> 1) & 3)) * 16;  // swizzled chunk byte-off

    // XCD-chunked block swizzle (T1, bijective: 1024 = 8 XCD x 128):
    // each XCD owns a contiguous M-range, x-fast within it, so the 8
    // column-blocks sharing an A row-panel hit the same L2.
    const int bid = blockIdx.x;
    const int xcd = bid & 7;
    const int idx = bid >> 3;              // 0..127 within XCD
    const int tileN = (idx & 7) * BN;
    const int tileM = ((idx >> 3) + (xcd << 4)) * BM;

    // staging source byte offsets: slot s, row r=s>>2 (4 chunks/row),
    // global chunk cg = (s&3) ^ ((r>>1)&3) (inverse swizzle).
    const int ra = tid >> 2;                       // A row 0..127
    const int ca = (tid & 3) ^ ((ra >> 1) & 3);
    const unsigned a_off = (unsigned)(tileM + ra) * K_DIM + ca * 16;
    unsigned b_off[2];
#pragma unroll
    for (int e = 0; e < 2; ++e) {
        const int s  = e * 512 + tid;
        const int rb = s >> 2;                     // B row 0..255
        const int cb = (s & 3) ^ ((rb >> 1) & 3);
        b_off[e] = (unsigned)(tileN + rb) * K_DIM + cb * 16;
    }

    i32x4 acc[4][4] = {};
    i32x4 af[4], bf[4];

#define STAGE(nbp, kk0) do {                                                   \
    async_copy16(A  + a_off    + (kk0), &As[nbp][tid * 16]);                   \
    async_copy16(Bt + b_off[0] + (kk0), &Bs[nbp][tid * 16]);                   \
    async_copy16(Bt + b_off[1] + (kk0), &Bs[nbp][8192 + tid * 16]);            \
} while (0)

    // ---- prologue: stage tile 0 into buf0 (3 loads in flight) ----
    STAGE(0, 0);

    int k1 = 0;

#define GROUP(bp, DS, WV) {                                                    \
    const int8_t* Ac = As[(bp)];                                               \
    const int8_t* Bc = Bs[(bp)];                                               \
    if (DS) { STAGE((bp) ^ 1, k1); }                                           \
    asm volatile("s_waitcnt vmcnt(" WV ")\n\ts_barrier" ::: "memory");         \
    _Pragma("unroll")                                                          \
    for (int i = 0; i < 4; ++i)                                                \
        af[i] = *(const i32x4*)(Ac + (wm + i * 16 + fr) * 64 + cs16);          \
    _Pragma("unroll")                                                          \
    for (int j = 0; j < 4; ++j)                                                \
        bf[j] = *(const i32x4*)(Bc + (wn + j * 16 + fr) * 64 + cs16);          \
    _Pragma("unroll")                                                          \
    for (int i = 0; i < 4; ++i) {                                              \
        _Pragma("unroll")                                                      \
        for (int j = 0; j < 4; ++j)                                            \
            acc[i][j] = __builtin_amdgcn_mfma_i32_16x16x64_i8(                 \
                af[i], bf[j], acc[i][j], 0, 0, 0);                             \
    }                                                                          \
    asm volatile("s_barrier" ::: "memory");                                    \
}

#pragma unroll 1
    for (int t = 0; t < NT - 1; ++t) {
        k1 = (t + 1) * BK;
        GROUP(t & 1, 1, "3");
    }
    GROUP((NT - 1) & 1, 0, "0");

#undef GROUP
#undef STAGE

    // ---- epilogue: C/D layout col=lane&15, row=(lane>>4)*4+reg ----
    const int cl = lane & 15;
    const int qr = lane >> 4;
#pragma unroll
    for (int j = 0; j < 4; ++j) {
        const int n  = tileN + wn + j * 16 + cl;
        const float al = alpha[n];
        const float bi = bias[n];
#pragma unroll
        for (int i = 0; i < 4; ++i) {
            const int mbase = tileM + wm + i * 16 + qr * 4;
#pragma unroll
            for (int r = 0; r < 4; ++r) {
                out[(size_t)(mbase + r) * N_DIM + n] =
                    al * (float)acc[i][j][r] + bi;
            }
        }
    }
}

// ---------------------------------------------------------------------------
extern "C" void kernel_launch(void* const* d_in, const int* in_sizes, int n_in,
                              void* d_out, int out_size, void* d_ws, size_t ws_size,
                              hipStream_t stream) {
    const float* x = (const float*)d_in[0];   // [4,4096,2048] fp32
    const float* W = (const float*)d_in[1];   // [2048,2048]  fp32
    const float* b = (const float*)d_in[2];   // [2048]       fp32
    float* out = (float*)d_out;               // [4,4096,2048] fp32

    // workspace layout: xq (32 MiB) | wcode (4 MiB) | alpha (8 KiB)
    int8_t* xq    = (int8_t*)d_ws;
    int8_t* wcode = xq + (size_t)M_DIM * K_DIM;
    float*  alpha = (float*)(wcode + (size_t)N_DIM * K_DIM);

    // 2048 wquant blocks + 8192 xquant blocks in one launch
    quant_kernel<<<N_DIM + 8192, 256, 0, stream>>>(W, x, wcode, alpha, xq);

    // 1-D grid, XCD-chunk swizzled inside the kernel: (M/128)*(N/256) = 1024
    gemm_kernel<<<1024, dim3(512), 0, stream>>>(xq, wcode, alpha, b, out);
}